// Round 6
// baseline (223.482 us; speedup 1.0000x reference)
//
#include <hip/hip_runtime.h>
#include <hip/hip_bf16.h>

// B=16384 W=5 L=20 E=50 V=100000 C=128 H=4096 O=50
// ha   = bf16 [16384][256] (K: 250 data + [250]=1.0 bias + pad)  ws+0     (8 MB)
// wbf  = bf16 fc1 weights in MFMA A-frag layout:                 ws+8M    (2 MB)
//        frag f = CT*8 + ks (CT = n>>4, ks = k>>5); lane = q*16+m
//        short at (f*64 + lane)*8 + j  == wb[CT*16+m][ks*32+q*8+j]
// w2bf = bf16 fc2 weights in MFMA B-frag layout:                 ws+10M   (0.5 MB)
//        frag f = kst*4 + Ot; short at (f*64+lane)*8+j == w2b[Ot*16+m][kst*32+q*8+j]
// gt   = fp32 [128][156]                                         ws+11M   (78 KB)
// gpart= fp32 [512][64][64] fc2 logit partials (per kh-half)     ws+16M   (8 MB)
// h (16384x4096) never hits HBM.
// R5 post-mortem: VGPR=92 -> av STILL demoted (3rd time); 256 blocks = 1
// block/CU so fetch-drain + barrier skew fully exposed (6.6k cyc/chunk vs
// ~2.2k work). R6: K-split blocks (512 blocks, kh half each, 16 chunks) ->
// 2 blocks/CU; waves re-split 4row x 2col so per-wave state = av 32 + acc2 32
// + acc 16 ~ 120 VGPR fits the 128 cap; Bs single 64KB + hs 16KB = 80KB LDS;
// prefetch issued post-mid-barrier, drained at end-of-chunk __syncthreads,
// stall covered by the co-resident block (m114). combine kernel: add halves
// + bias + softmax.

typedef __attribute__((ext_vector_type(8))) short short8;
typedef __attribute__((ext_vector_type(4))) float float4v;

__device__ inline short bf16b(float f) {
    __hip_bfloat16 h = __float2bfloat16(f);
    return *reinterpret_cast<short*>(&h);
}
__device__ inline uint packbf2(float a, float b) {
    return (uint)(ushort)bf16b(a) | ((uint)(ushort)bf16b(b) << 16);
}
__device__ inline void gload_lds16(const void* g, void* l) {
    __builtin_amdgcn_global_load_lds(
        (const __attribute__((address_space(1))) unsigned int*)g,
        (__attribute__((address_space(3))) unsigned int*)l, 16, 0, 0);
}

// ---------------------------------------------------------------------------
// Merged prep: wbf (blocks 0..4095), w2bf (..5119), gt (..5194), haPad (..5578)
// ---------------------------------------------------------------------------
__global__ __launch_bounds__(256) void prep_kernel(
    const float* __restrict__ fc1_w, const float* __restrict__ fc1_b,
    const float* __restrict__ fc2_w, const float* __restrict__ char_emb,
    const float* __restrict__ conv_w, short* __restrict__ wbf,
    short* __restrict__ w2bf, float* __restrict__ gt,
    __hip_bfloat16* __restrict__ ha)
{
    const int bid = blockIdx.x;
    if (bid < 4096) {                       // fc1 weights+bias -> frag order
        int idx = bid * 256 + threadIdx.x;  // n*256 + k
        int n = idx >> 8, k = idx & 255;
        float v = (k < 250) ? fc1_w[n * 250 + k] : (k == 250 ? fc1_b[n] : 0.f);
        int CT = n >> 4, mm = n & 15;
        int ks = k >> 5, qq = (k >> 3) & 3, j = k & 7;
        wbf[((CT * 8 + ks) * 64 + qq * 16 + mm) * 8 + j] = bf16b(v);
    } else if (bid < 5120) {                // fc2 weights (pad 64) -> frag order
        int idx = (bid - 4096) * 256 + threadIdx.x;   // o*4096 + k
        int o = idx >> 12, k = idx & 4095;
        float v = (o < 50) ? fc2_w[idx] : 0.f;
        int Ot = o >> 4, mm = o & 15;
        int kst = k >> 5, qq = (k >> 3) & 3, j = k & 7;
        w2bf[((kst * 4 + Ot) * 64 + qq * 16 + mm) * 8 + j] = bf16b(v);
    } else if (bid < 5195) {                // conv lookup table
        int idx = (bid - 5120) * 256 + threadIdx.x;   // < 19200
        if (idx >= 19200) return;
        int c = idx / 150, rem = idx - c * 150;
        int kk = rem / 50, o = rem - kk * 50;
        const float* ce = char_emb + c * 50;
        const float* w  = conv_w + o * 150 + kk;
        float s = 0.f;
        #pragma unroll 10
        for (int i = 0; i < 50; ++i) s += ce[i] * w[i * 3];
        gt[c * 156 + kk * 52 + o] = s;
    } else {                                // ha pad cols 250..255
        int idx = (bid - 5195) * 256 + threadIdx.x;   // b*6 + j
        int b = idx / 6, j = idx - b * 6;
        ha[b * 256 + 250 + j] = __float2bfloat16(j == 0 ? 1.f : 0.f);
    }
}

// ---------------------------------------------------------------------------
// conv via table lookup (unchanged, proven R7). Block = 512 thr = 32 words.
// ---------------------------------------------------------------------------
__global__ __launch_bounds__(512) void conv_kernel(
    const int* __restrict__ x, const int* __restrict__ wci,
    const float* __restrict__ word_emb, const float* __restrict__ conv_b,
    const float* __restrict__ gt, __hip_bfloat16* __restrict__ ha)
{
    __shared__ float Gs[19968];       // 79,872 B
    __shared__ uint  cpack[160];
    __shared__ int   xs[32];

    const int tid = threadIdx.x;
    const int gw0 = blockIdx.x * 32;

    int xr = 0;
    if (tid < 32) xr = x[gw0 + tid];

    #pragma unroll
    for (int t = 0; t < 39; ++t)
        Gs[t * 512 + tid] = gt[t * 512 + tid];

    if (tid < 32) {
        const int* crow = wci + xr * 20;
        int cid[20];
        #pragma unroll
        for (int p = 0; p < 20; ++p) cid[p] = crow[p];
        #pragma unroll
        for (int u = 0; u < 5; ++u)
            cpack[tid * 5 + u] = (uint)cid[u * 4] | ((uint)cid[u * 4 + 1] << 8)
                               | ((uint)cid[u * 4 + 2] << 16) | ((uint)cid[u * 4 + 3] << 24);
        xs[tid] = xr;
    }
    __syncthreads();

    const int lane = tid & 63;
    const int wv   = tid >> 6;
    const int t    = lane & 15;
    const int w    = lane >> 4;
    const int tc   = (t < 13) ? t : 12;
    const int widx = wv * 4 + w;

    uint cw[5];
    #pragma unroll
    for (int u = 0; u < 5; ++u) cw[u] = cpack[widx * 5 + u];
    int ca[20];
    #pragma unroll
    for (int p = 0; p < 20; ++p)
        ca[p] = (int)((cw[p >> 2] >> ((p & 3) * 8)) & 0xFF) * 156;

    const int tc4 = tc * 4;
    float4 mx;
    {
        float4 v = *(const float4*)&Gs[ca[0] + 52 + tc4];
        float4 u = *(const float4*)&Gs[ca[1] + 104 + tc4];
        mx.x = v.x + u.x; mx.y = v.y + u.y; mx.z = v.z + u.z; mx.w = v.w + u.w;
    }
    #pragma unroll
    for (int l = 1; l < 19; ++l) {
        float4 v = *(const float4*)&Gs[ca[l] + 52 + tc4];
        float4 a = *(const float4*)&Gs[ca[l - 1] + tc4];
        float4 b = *(const float4*)&Gs[ca[l + 1] + 104 + tc4];
        float vx = v.x + a.x + b.x, vy = v.y + a.y + b.y;
        float vz = v.z + a.z + b.z, vw = v.w + a.w + b.w;
        mx.x = fmaxf(mx.x, vx); mx.y = fmaxf(mx.y, vy);
        mx.z = fmaxf(mx.z, vz); mx.w = fmaxf(mx.w, vw);
    }
    {
        float4 v = *(const float4*)&Gs[ca[19] + 52 + tc4];
        float4 a = *(const float4*)&Gs[ca[18] + tc4];
        mx.x = fmaxf(mx.x, v.x + a.x); mx.y = fmaxf(mx.y, v.y + a.y);
        mx.z = fmaxf(mx.z, v.z + a.z); mx.w = fmaxf(mx.w, v.w + a.w);
    }

    const int xid = xs[widx];
    const float* wer = word_emb + (size_t)xid * 50 + tc4;
    float2 wea = *(const float2*)wer;
    float2 web = make_float2(0.f, 0.f);
    float2 cba = *(const float2*)(conv_b + tc4);
    float2 cbb = make_float2(0.f, 0.f);
    if (tc < 12) {
        web = *(const float2*)(wer + 2);
        cbb = *(const float2*)(conv_b + tc4 + 2);
    }
    const int gw = gw0 + widx, b = gw / 5, wp = gw - b * 5;
    __hip_bfloat16* dst = ha + b * 256 + wp * 50 + tc4;
    uint lo = packbf2(mx.x + cba.x + wea.x, mx.y + cba.y + wea.y);
    if (t < 12) {
        uint hi = packbf2(mx.z + cbb.x + web.x, mx.w + cbb.y + web.y);
        *(uint*)dst = lo;
        *((uint*)dst + 1) = hi;
    } else if (t == 12) {
        *(uint*)dst = lo;
    }
}

// ---------------------------------------------------------------------------
// Fused fc1 + tanh + fc2-partial. 512 blocks x 512 thr.
// Block = (rg = bid>>1: 64 rows at rg*64) x (kh = bid&1: chunks [kh*16,+16)).
// Waves: wr = wv>>1 (row quarter, 16 rows), wc = wv&1 (col half, 64 cols).
// fc2 reuses (wr,wc) as (k-slice, out-half).
// LDS 80KB (Bs 64KB single + hs 16KB) -> 2 blocks/CU; VGPR target <=128.
// Per chunk: b2 loads (top) ; fc1 (av regs x Bs) ; tanh->hs ; lgkm barrier ;
// issue gload B(ch+1) into Bs ; fc2 (hs + b2, setprio) ; __syncthreads
// (vmcnt drain covered by co-resident block).
// ---------------------------------------------------------------------------
__global__ __launch_bounds__(512, 2) void fused_kernel(
    const __hip_bfloat16* __restrict__ ha, const short* __restrict__ wbf,
    const short* __restrict__ w2bf, float* __restrict__ gpart)
{
    __shared__ char smem[81920];                 // 80 KB
    short8* Bsv = (short8*)smem;                 // 4096 frags (64 KB)
    char*   hsb = smem + 65536;                  // 16 KB
    float*  partf = (float*)smem;                // [4][64][64] epilogue alias

    const int tid  = threadIdx.x;
    const int lane = tid & 63;
    const int wv   = tid >> 6;
    const int wr = wv >> 1, wc = wv & 1;
    const int q = lane >> 4, m = lane & 15;
    const int rg = blockIdx.x >> 1, kh = blockIdx.x & 1;
    const int m0 = rg * 64;
    const int ch0 = kh * 16;

    const short8* wbfv  = (const short8*)wbf;
    const short8* w2bfv = (const short8*)w2bf;
    const short8* hav   = (const short8*)ha;

    // ---- A-frags: wave's 16 rows x K=256: 8 frags = 32 VGPR, pinned ----
    short8 av[8];
    #pragma unroll
    for (int ks = 0; ks < 8; ++ks)
        av[ks] = hav[(size_t)(m0 + wr * 16 + m) * 32 + ks * 4 + q];
    #pragma unroll
    for (int ks = 0; ks < 8; ++ks)
        asm volatile("" : "+v"(av[ks]));

    // ---- prologue: stage B(ch0) into Bs ----
    #pragma unroll
    for (int i = 0; i < 8; ++i)
        gload_lds16(wbfv + (size_t)ch0 * 4096 + i * 512 + tid,
                    Bsv + i * 512 + tid);
    __syncthreads();                             // vmcnt drained -> Bs ready

    float4v acc2[4][2] = {};    // fc2 accum: [row-tile][out-col-pair]

    for (int chl = 0; chl < 16; ++chl) {
        const int ch = ch0 + chl;

        // b2 for this chunk, issued first (oldest vmem -> waited without
        // draining the later prefetch)
        short8 b2[2];
        #pragma unroll
        for (int Otp = 0; Otp < 2; ++Otp)
            b2[Otp] = w2bfv[(size_t)((ch * 4 + wr) * 4 + wc * 2 + Otp) * 64 + lane];

        // ---- fc1: rows [wr*16,+16) x cols [ch*128 + wc*64, +64) ----
        float4v acc[4] = {};
        #pragma unroll
        for (int ks = 0; ks < 8; ++ks) {
            short8 bv[4];
            #pragma unroll
            for (int nt = 0; nt < 4; ++nt)
                bv[nt] = Bsv[((wc * 4 + nt) * 8 + ks) * 64 + lane];
            #pragma unroll
            for (int nt = 0; nt < 4; ++nt)
                acc[nt] = __builtin_amdgcn_mfma_f32_16x16x32_bf16(
                    bv[nt], av[ks], acc[nt], 0, 0, 0);
        }

        // ---- tanh + pack to fc2-A-frag layout in hs ----
        const int q2base = q >> 1, slot = q & 1;
        #pragma unroll
        for (int nt = 0; nt < 4; ++nt) {
            float tv[4];
            #pragma unroll
            for (int r = 0; r < 4; ++r)
                tv[r] = 1.f - 2.f / (__expf(2.f * acc[nt][r]) + 1.f);
            const int ks2l = wc * 2 + (nt >> 1);
            const int q2 = (nt & 1) * 2 + q2base;
            const uint p0 = packbf2(tv[0], tv[1]);
            const uint p1 = packbf2(tv[2], tv[3]);
            *(uint2*)(hsb + (((wr * 4 + ks2l) * 64 + q2 * 16 + m) * 16 + slot * 8))
                = make_uint2(p0, p1);
        }

        // mid-chunk barrier: hs visible, Bs ds-reads drained (lgkm only)
        asm volatile("s_waitcnt lgkmcnt(0)" ::: "memory");
        __builtin_amdgcn_sched_barrier(0);
        __builtin_amdgcn_s_barrier();

        // issue prefetch of B(ch+1) into Bs (reads drained; lands by the
        // end-of-chunk __syncthreads, stall covered by co-resident block)
        if (chl < 15) {
            #pragma unroll
            for (int i = 0; i < 8; ++i)
                gload_lds16(wbfv + (size_t)(ch + 1) * 4096 + i * 512 + tid,
                            Bsv + i * 512 + tid);
        }

        // ---- fc2 partial: k-slice [ch*128 + wr*32, +32), outs [wc*32,+32) ----
        {
            short8 a2[4];
            #pragma unroll
            for (int Rl = 0; Rl < 4; ++Rl)
                a2[Rl] = *(const short8*)(hsb + ((Rl * 4 + wr) * 64 + lane) * 16);
            __builtin_amdgcn_s_setprio(1);
            #pragma unroll
            for (int Rl = 0; Rl < 4; ++Rl)
                #pragma unroll
                for (int Otp = 0; Otp < 2; ++Otp)
                    acc2[Rl][Otp] = __builtin_amdgcn_mfma_f32_16x16x32_bf16(
                        a2[Rl], b2[Otp], acc2[Rl][Otp], 0, 0, 0);
            __builtin_amdgcn_s_setprio(0);
        }

        __syncthreads();    // drains vmcnt (prefetch) + hs reads done
    }

    // ---- epilogue: spill k-partials, reduce over wr, write gpart ----
    #pragma unroll
    for (int Rl = 0; Rl < 4; ++Rl)
        #pragma unroll
        for (int Otp = 0; Otp < 2; ++Otp)
            #pragma unroll
            for (int r = 0; r < 4; ++r)
                partf[(size_t)wr * 4096 + (Rl * 16 + q * 4 + r) * 64
                      + wc * 32 + Otp * 16 + m] = acc2[Rl][Otp][r];
    __syncthreads();

    #pragma unroll
    for (int t = 0; t < 8; ++t) {
        int idx = t * 512 + tid;           // row*64 + col, 4096 entries
        float s = partf[idx] + partf[4096 + idx]
                + partf[8192 + idx] + partf[12288 + idx];
        gpart[(size_t)blockIdx.x * 4096 + idx] = s;
    }
}

// ---------------------------------------------------------------------------
// combine: sum the two kh halves, + bias, softmax, write out.
// 512 blocks x 256 thr; block handles 32 rows, wave 8 rows, lane = col.
// ---------------------------------------------------------------------------
__global__ __launch_bounds__(256) void combine_kernel(
    const float* __restrict__ gpart, const float* __restrict__ fc2_b,
    float* __restrict__ out)
{
    const int tid  = threadIdx.x;
    const int lane = tid & 63;
    const int wv   = tid >> 6;
    const float bias = (lane < 50) ? fc2_b[lane] : 0.f;

    #pragma unroll
    for (int rr = 0; rr < 8; ++rr) {
        const int row = blockIdx.x * 32 + wv * 8 + rr;
        const int rg = row >> 6, rl = row & 63;
        float v = gpart[(size_t)(rg * 2) * 4096 + rl * 64 + lane]
                + gpart[(size_t)(rg * 2 + 1) * 4096 + rl * 64 + lane];
        v = (lane < 50) ? v + bias : -1e30f;
        float mx = v;
        #pragma unroll
        for (int off = 32; off > 0; off >>= 1) mx = fmaxf(mx, __shfl_xor(mx, off));
        float e = __expf(v - mx);
        float s = e;
        #pragma unroll
        for (int off = 32; off > 0; off >>= 1) s += __shfl_xor(s, off);
        if (lane < 50)
            out[(size_t)row * 50 + lane] = e / s;
    }
}

// ---------------------------------------------------------------------------
extern "C" void kernel_launch(void* const* d_in, const int* in_sizes, int n_in,
                              void* d_out, int out_size, void* d_ws, size_t ws_size,
                              hipStream_t stream) {
    const int*   x        = (const int*)  d_in[0];
    const int*   wci      = (const int*)  d_in[1];
    const float* word_emb = (const float*)d_in[2];
    const float* char_emb = (const float*)d_in[3];
    const float* conv_w   = (const float*)d_in[4];
    const float* conv_b   = (const float*)d_in[5];
    const float* fc1_w    = (const float*)d_in[6];
    const float* fc1_b    = (const float*)d_in[7];
    const float* fc2_w    = (const float*)d_in[8];
    const float* fc2_b    = (const float*)d_in[9];
    float* out = (float*)d_out;

    char* ws = (char*)d_ws;
    __hip_bfloat16* ha  = (__hip_bfloat16*)ws;                        // 8 MB
    short* wbf   = (short*)(ws + ((size_t)8  << 20));                 // 2 MB
    short* w2bf  = (short*)(ws + ((size_t)10 << 20));                 // 0.5 MB
    float* gtp   = (float*)(ws + ((size_t)11 << 20));                 // 78 KB
    float* gpart = (float*)(ws + ((size_t)16 << 20));                 // 8 MB

    prep_kernel<<<5579, 256, 0, stream>>>(fc1_w, fc1_b, fc2_w, char_emb,
                                          conv_w, wbf, w2bf, gtp, ha);
    conv_kernel<<<2560, 512, 0, stream>>>(x, wci, word_emb, conv_b, gtp, ha);
    fused_kernel<<<512, 512, 0, stream>>>(ha, wbf, w2bf, gpart);
    combine_kernel<<<512, 256, 0, stream>>>(gpart, fc2_b, out);
}

// Round 7
// 214.507 us; speedup vs baseline: 1.0418x; 1.0418x over previous
//
#include <hip/hip_runtime.h>
#include <hip/hip_bf16.h>

// B=16384 W=5 L=20 E=50 V=100000 C=128 H=4096 O=50
// ha   = bf16 [16384][256] (K: 250 data + [250]=1.0 bias + pad)  ws+0     (8 MB)
// wbf  = bf16 fc1 weights in MFMA A-frag layout:                 ws+8M    (2 MB)
//        frag f = CT*8 + ks (CT = n>>4, ks = k>>5); lane = q*16+m
//        short at (f*64 + lane)*8 + j  == wb[CT*16+m][ks*32+q*8+j]
// w2bf = bf16 fc2 weights in MFMA B-frag layout:                 ws+10M   (0.5 MB)
//        frag f = kst*4 + Ot; short at (f*64+lane)*8+j == w2b[Ot*16+m][kst*32+q*8+j]
// gt   = fp32 [128][156]                                         ws+11M   (78 KB)
// gpart= fp32 [512][64][64] fc2 logit partials (per kh-half)     ws+16M   (8 MB)
// h (16384x4096) never hits HBM.
// R6 post-mortem: 2 barriers/chunk + cross-wave hs handoff -> lockstep phase
// serialization (MfmaUtil 18 / VALU 41 / LDS ~35%, nothing saturated), VGPR
// still 72. R7: wave-PRIVATE handoff (R3-proven: wave's fc1 cols == its fc2
// k-frag, same-wave LDS write->read needs no barrier) -> ONE barrier/chunk
// (Bs dbuf flip). 512thr, 64 rows, 128-col chunks, waves 2x4 (wr,wc).
// launch_bounds(512,2) -> VGPR cap 256 so av[2][8]+acc2[2][4] (~170 live)
// finally fits. LDS 144KB = Bs 2x64K + hs 16K; part[4][64][64] aliases Bs.

typedef __attribute__((ext_vector_type(8))) short short8;
typedef __attribute__((ext_vector_type(4))) float float4v;

__device__ inline short bf16b(float f) {
    __hip_bfloat16 h = __float2bfloat16(f);
    return *reinterpret_cast<short*>(&h);
}
__device__ inline uint packbf2(float a, float b) {
    return (uint)(ushort)bf16b(a) | ((uint)(ushort)bf16b(b) << 16);
}
__device__ inline void gload_lds16(const void* g, void* l) {
    __builtin_amdgcn_global_load_lds(
        (const __attribute__((address_space(1))) unsigned int*)g,
        (__attribute__((address_space(3))) unsigned int*)l, 16, 0, 0);
}

// ---------------------------------------------------------------------------
// Merged prep: wbf (blocks 0..4095), w2bf (..5119), gt (..5194), haPad (..5578)
// ---------------------------------------------------------------------------
__global__ __launch_bounds__(256) void prep_kernel(
    const float* __restrict__ fc1_w, const float* __restrict__ fc1_b,
    const float* __restrict__ fc2_w, const float* __restrict__ char_emb,
    const float* __restrict__ conv_w, short* __restrict__ wbf,
    short* __restrict__ w2bf, float* __restrict__ gt,
    __hip_bfloat16* __restrict__ ha)
{
    const int bid = blockIdx.x;
    if (bid < 4096) {                       // fc1 weights+bias -> frag order
        int idx = bid * 256 + threadIdx.x;  // n*256 + k
        int n = idx >> 8, k = idx & 255;
        float v = (k < 250) ? fc1_w[n * 250 + k] : (k == 250 ? fc1_b[n] : 0.f);
        int CT = n >> 4, mm = n & 15;
        int ks = k >> 5, qq = (k >> 3) & 3, j = k & 7;
        wbf[((CT * 8 + ks) * 64 + qq * 16 + mm) * 8 + j] = bf16b(v);
    } else if (bid < 5120) {                // fc2 weights (pad 64) -> frag order
        int idx = (bid - 4096) * 256 + threadIdx.x;   // o*4096 + k
        int o = idx >> 12, k = idx & 4095;
        float v = (o < 50) ? fc2_w[idx] : 0.f;
        int Ot = o >> 4, mm = o & 15;
        int kst = k >> 5, qq = (k >> 3) & 3, j = k & 7;
        w2bf[((kst * 4 + Ot) * 64 + qq * 16 + mm) * 8 + j] = bf16b(v);
    } else if (bid < 5195) {                // conv lookup table
        int idx = (bid - 5120) * 256 + threadIdx.x;   // < 19200
        if (idx >= 19200) return;
        int c = idx / 150, rem = idx - c * 150;
        int kk = rem / 50, o = rem - kk * 50;
        const float* ce = char_emb + c * 50;
        const float* w  = conv_w + o * 150 + kk;
        float s = 0.f;
        #pragma unroll 10
        for (int i = 0; i < 50; ++i) s += ce[i] * w[i * 3];
        gt[c * 156 + kk * 52 + o] = s;
    } else {                                // ha pad cols 250..255
        int idx = (bid - 5195) * 256 + threadIdx.x;   // b*6 + j
        int b = idx / 6, j = idx - b * 6;
        ha[b * 256 + 250 + j] = __float2bfloat16(j == 0 ? 1.f : 0.f);
    }
}

// ---------------------------------------------------------------------------
// conv via table lookup (unchanged, proven R7). Block = 512 thr = 32 words.
// ---------------------------------------------------------------------------
__global__ __launch_bounds__(512) void conv_kernel(
    const int* __restrict__ x, const int* __restrict__ wci,
    const float* __restrict__ word_emb, const float* __restrict__ conv_b,
    const float* __restrict__ gt, __hip_bfloat16* __restrict__ ha)
{
    __shared__ float Gs[19968];       // 79,872 B
    __shared__ uint  cpack[160];
    __shared__ int   xs[32];

    const int tid = threadIdx.x;
    const int gw0 = blockIdx.x * 32;

    int xr = 0;
    if (tid < 32) xr = x[gw0 + tid];

    #pragma unroll
    for (int t = 0; t < 39; ++t)
        Gs[t * 512 + tid] = gt[t * 512 + tid];

    if (tid < 32) {
        const int* crow = wci + xr * 20;
        int cid[20];
        #pragma unroll
        for (int p = 0; p < 20; ++p) cid[p] = crow[p];
        #pragma unroll
        for (int u = 0; u < 5; ++u)
            cpack[tid * 5 + u] = (uint)cid[u * 4] | ((uint)cid[u * 4 + 1] << 8)
                               | ((uint)cid[u * 4 + 2] << 16) | ((uint)cid[u * 4 + 3] << 24);
        xs[tid] = xr;
    }
    __syncthreads();

    const int lane = tid & 63;
    const int wv   = tid >> 6;
    const int t    = lane & 15;
    const int w    = lane >> 4;
    const int tc   = (t < 13) ? t : 12;
    const int widx = wv * 4 + w;

    uint cw[5];
    #pragma unroll
    for (int u = 0; u < 5; ++u) cw[u] = cpack[widx * 5 + u];
    int ca[20];
    #pragma unroll
    for (int p = 0; p < 20; ++p)
        ca[p] = (int)((cw[p >> 2] >> ((p & 3) * 8)) & 0xFF) * 156;

    const int tc4 = tc * 4;
    float4 mx;
    {
        float4 v = *(const float4*)&Gs[ca[0] + 52 + tc4];
        float4 u = *(const float4*)&Gs[ca[1] + 104 + tc4];
        mx.x = v.x + u.x; mx.y = v.y + u.y; mx.z = v.z + u.z; mx.w = v.w + u.w;
    }
    #pragma unroll
    for (int l = 1; l < 19; ++l) {
        float4 v = *(const float4*)&Gs[ca[l] + 52 + tc4];
        float4 a = *(const float4*)&Gs[ca[l - 1] + tc4];
        float4 b = *(const float4*)&Gs[ca[l + 1] + 104 + tc4];
        float vx = v.x + a.x + b.x, vy = v.y + a.y + b.y;
        float vz = v.z + a.z + b.z, vw = v.w + a.w + b.w;
        mx.x = fmaxf(mx.x, vx); mx.y = fmaxf(mx.y, vy);
        mx.z = fmaxf(mx.z, vz); mx.w = fmaxf(mx.w, vw);
    }
    {
        float4 v = *(const float4*)&Gs[ca[19] + 52 + tc4];
        float4 a = *(const float4*)&Gs[ca[18] + tc4];
        mx.x = fmaxf(mx.x, v.x + a.x); mx.y = fmaxf(mx.y, v.y + a.y);
        mx.z = fmaxf(mx.z, v.z + a.z); mx.w = fmaxf(mx.w, v.w + a.w);
    }

    const int xid = xs[widx];
    const float* wer = word_emb + (size_t)xid * 50 + tc4;
    float2 wea = *(const float2*)wer;
    float2 web = make_float2(0.f, 0.f);
    float2 cba = *(const float2*)(conv_b + tc4);
    float2 cbb = make_float2(0.f, 0.f);
    if (tc < 12) {
        web = *(const float2*)(wer + 2);
        cbb = *(const float2*)(conv_b + tc4 + 2);
    }
    const int gw = gw0 + widx, b = gw / 5, wp = gw - b * 5;
    __hip_bfloat16* dst = ha + b * 256 + wp * 50 + tc4;
    uint lo = packbf2(mx.x + cba.x + wea.x, mx.y + cba.y + wea.y);
    if (t < 12) {
        uint hi = packbf2(mx.z + cbb.x + web.x, mx.w + cbb.y + web.y);
        *(uint*)dst = lo;
        *((uint*)dst + 1) = hi;
    } else if (t == 12) {
        *(uint*)dst = lo;
    }
}

// ---------------------------------------------------------------------------
// Fused fc1 + tanh + fc2-partial. 512 blocks x 512 thr.
// Block = (rg = bid>>1: 64 rows) x (kh = bid&1: 16 chunks of 128 h-cols).
// Waves 2x4: wr = wv>>2 (row half), wc = wv&3 (col quarter = fc2 k-frag kf).
// WAVE-PRIVATE handoff: wave writes hs frags (wr*2+mt, wc) and reads exactly
// those for fc2 -> no mid-chunk barrier (same-wave LDS RAW is ordered).
// One __syncthreads per chunk = Bs dbuf flip + vmcnt drain of the prefetch.
// ---------------------------------------------------------------------------
__global__ __launch_bounds__(512, 2) void fused_kernel(
    const __hip_bfloat16* __restrict__ ha, const short* __restrict__ wbf,
    const short* __restrict__ w2bf, float* __restrict__ gpart)
{
    __shared__ char smem[147456];                // 144 KB
    short8* Bsv = (short8*)smem;                 // [2][4096] frags (2x64KB)
    char*   hsb = smem + 131072;                 // 16 KB (16 frags)
    float*  partf = (float*)smem;                // [4][64][64] epilogue alias

    const int tid  = threadIdx.x;
    const int lane = tid & 63;
    const int wv   = tid >> 6;
    const int wr = wv >> 2, wc = wv & 3;
    const int q = lane >> 4, m = lane & 15;
    const int rg = blockIdx.x >> 1, kh = blockIdx.x & 1;
    const int m0 = rg * 64;

    const short8* wbfv  = (const short8*)wbf;
    const short8* w2bfv = (const short8*)w2bf;
    const short8* hav   = (const short8*)ha;

    // ---- A-frags: wave's 32 rows x K=256: 16 frags = 64 VGPR, pinned ----
    short8 av[2][8];
    #pragma unroll
    for (int mt = 0; mt < 2; ++mt)
        #pragma unroll
        for (int ks = 0; ks < 8; ++ks)
            av[mt][ks] = hav[(size_t)(m0 + wr * 32 + mt * 16 + m) * 32 + ks * 4 + q];
    #pragma unroll
    for (int mt = 0; mt < 2; ++mt)
        #pragma unroll
        for (int ks = 0; ks < 8; ++ks)
            asm volatile("" : "+v"(av[mt][ks]));

    // ---- prologue: stage chunk kh*16 into Bs[0] (64KB, 8 gloads/thread) ----
    #pragma unroll
    for (int i = 0; i < 8; ++i)
        gload_lds16(wbfv + (size_t)(kh * 16) * 4096 + i * 512 + tid,
                    Bsv + i * 512 + tid);
    __syncthreads();

    float4v acc2[2][4] = {};    // fc2 partial: [row-tile mt][out-tile], k = wc

    for (int chl = 0; chl < 16; ++chl) {
        const int buf = chl & 1;
        const int chg = kh * 16 + chl;

        // b2 for this chunk's wave k-frag (kst = chg*4 + wc), issued first
        short8 b2[4];
        #pragma unroll
        for (int Ot = 0; Ot < 4; ++Ot)
            b2[Ot] = w2bfv[(size_t)((chg * 4 + wc) * 4 + Ot) * 64 + lane];

        // async prefetch of next chunk into the other buffer
        if (chl < 15) {
            #pragma unroll
            for (int i = 0; i < 8; ++i)
                gload_lds16(wbfv + (size_t)(chg + 1) * 4096 + i * 512 + tid,
                            Bsv + (buf ^ 1) * 4096 + i * 512 + tid);
        }

        // ---- fc1: rows [wr*32,+32) x cols [chg*128 + wc*32, +32) ----
        float4v acc[2][2] = {};
        #pragma unroll
        for (int ks = 0; ks < 8; ++ks) {
            short8 bv[2];
            #pragma unroll
            for (int nt = 0; nt < 2; ++nt)
                bv[nt] = Bsv[buf * 4096 + ((wc * 2 + nt) * 8 + ks) * 64 + lane];
            #pragma unroll
            for (int mt = 0; mt < 2; ++mt)
                #pragma unroll
                for (int nt = 0; nt < 2; ++nt)
                    acc[mt][nt] = __builtin_amdgcn_mfma_f32_16x16x32_bf16(
                        bv[nt], av[mt][ks], acc[mt][nt], 0, 0, 0);
        }

        // ---- tanh + pack to own hs frags (rt = wr*2+mt, kf = wc) ----
        const int q2base = q >> 1, slot = q & 1;
        #pragma unroll
        for (int mt = 0; mt < 2; ++mt) {
            const int frag = (wr * 2 + mt) * 4 + wc;
            #pragma unroll
            for (int nt = 0; nt < 2; ++nt) {
                float tv[4];
                #pragma unroll
                for (int r = 0; r < 4; ++r)
                    tv[r] = 1.f - 2.f / (__expf(2.f * acc[mt][nt][r]) + 1.f);
                const int q2 = nt * 2 + q2base;
                const uint p0 = packbf2(tv[0], tv[1]);
                const uint p1 = packbf2(tv[2], tv[3]);
                *(uint2*)(hsb + ((frag * 64 + q2 * 16 + m) * 16 + slot * 8))
                    = make_uint2(p0, p1);
            }
        }

        // ---- fc2 partial: read back OWN frags (same-wave order, no bar) ----
        {
            short8 a2[2];
            #pragma unroll
            for (int mt = 0; mt < 2; ++mt)
                a2[mt] = *(const short8*)(hsb
                    + (((wr * 2 + mt) * 4 + wc) * 64 + lane) * 16);
            __builtin_amdgcn_s_setprio(1);
            #pragma unroll
            for (int mt = 0; mt < 2; ++mt)
                #pragma unroll
                for (int Ot = 0; Ot < 4; ++Ot)
                    acc2[mt][Ot] = __builtin_amdgcn_mfma_f32_16x16x32_bf16(
                        a2[mt], b2[Ot], acc2[mt][Ot], 0, 0, 0);
            __builtin_amdgcn_s_setprio(0);
        }

        // single barrier: all Bs[buf] reads done + prefetch vmcnt drained
        __syncthreads();
    }

    // ---- epilogue: spill per-wc k-partials, reduce, write gpart ----
    #pragma unroll
    for (int mt = 0; mt < 2; ++mt)
        #pragma unroll
        for (int Ot = 0; Ot < 4; ++Ot)
            #pragma unroll
            for (int r = 0; r < 4; ++r)
                partf[(size_t)wc * 4096
                      + ((wr * 2 + mt) * 16 + q * 4 + r) * 64 + Ot * 16 + m]
                    = acc2[mt][Ot][r];
    __syncthreads();

    #pragma unroll
    for (int t = 0; t < 8; ++t) {
        int idx = t * 512 + tid;           // row*64 + col
        float s = partf[idx] + partf[4096 + idx]
                + partf[8192 + idx] + partf[12288 + idx];
        gpart[(size_t)blockIdx.x * 4096 + idx] = s;
    }
}

// ---------------------------------------------------------------------------
// combine: sum the two kh halves, + bias, softmax, write out.
// 512 blocks x 256 thr; block handles 32 rows, wave 8 rows, lane = col.
// ---------------------------------------------------------------------------
__global__ __launch_bounds__(256) void combine_kernel(
    const float* __restrict__ gpart, const float* __restrict__ fc2_b,
    float* __restrict__ out)
{
    const int tid  = threadIdx.x;
    const int lane = tid & 63;
    const int wv   = tid >> 6;
    const float bias = (lane < 50) ? fc2_b[lane] : 0.f;

    #pragma unroll
    for (int rr = 0; rr < 8; ++rr) {
        const int row = blockIdx.x * 32 + wv * 8 + rr;
        const int rg = row >> 6, rl = row & 63;
        float v = gpart[(size_t)(rg * 2) * 4096 + rl * 64 + lane]
                + gpart[(size_t)(rg * 2 + 1) * 4096 + rl * 64 + lane];
        v = (lane < 50) ? v + bias : -1e30f;
        float mx = v;
        #pragma unroll
        for (int off = 32; off > 0; off >>= 1) mx = fmaxf(mx, __shfl_xor(mx, off));
        float e = __expf(v - mx);
        float s = e;
        #pragma unroll
        for (int off = 32; off > 0; off >>= 1) s += __shfl_xor(s, off);
        if (lane < 50)
            out[(size_t)row * 50 + lane] = e / s;
    }
}

// ---------------------------------------------------------------------------
extern "C" void kernel_launch(void* const* d_in, const int* in_sizes, int n_in,
                              void* d_out, int out_size, void* d_ws, size_t ws_size,
                              hipStream_t stream) {
    const int*   x        = (const int*)  d_in[0];
    const int*   wci      = (const int*)  d_in[1];
    const float* word_emb = (const float*)d_in[2];
    const float* char_emb = (const float*)d_in[3];
    const float* conv_w   = (const float*)d_in[4];
    const float* conv_b   = (const float*)d_in[5];
    const float* fc1_w    = (const float*)d_in[6];
    const float* fc1_b    = (const float*)d_in[7];
    const float* fc2_w    = (const float*)d_in[8];
    const float* fc2_b    = (const float*)d_in[9];
    float* out = (float*)d_out;

    char* ws = (char*)d_ws;
    __hip_bfloat16* ha  = (__hip_bfloat16*)ws;                        // 8 MB
    short* wbf   = (short*)(ws + ((size_t)8  << 20));                 // 2 MB
    short* w2bf  = (short*)(ws + ((size_t)10 << 20));                 // 0.5 MB
    float* gtp   = (float*)(ws + ((size_t)11 << 20));                 // 78 KB
    float* gpart = (float*)(ws + ((size_t)16 << 20));                 // 8 MB

    prep_kernel<<<5579, 256, 0, stream>>>(fc1_w, fc1_b, fc2_w, char_emb,
                                          conv_w, wbf, w2bf, gtp, ha);
    conv_kernel<<<2560, 512, 0, stream>>>(x, wci, word_emb, conv_b, gtp, ha);
    fused_kernel<<<512, 512, 0, stream>>>(ha, wbf, w2bf, gpart);
    combine_kernel<<<512, 256, 0, stream>>>(gpart, fc2_b, out);
}

// Round 8
// 204.382 us; speedup vs baseline: 1.0935x; 1.0495x over previous
//
#include <hip/hip_runtime.h>
#include <hip/hip_bf16.h>

// B=16384 W=5 L=20 E=50 V=100000 C=128 H=4096 O=50
// ha   = bf16 [16384][256] (K: 250 data + [250]=1.0 bias + pad)  ws+0     (8 MB)
// wbf  = bf16 fc1 weights in MFMA A-frag layout:                 ws+8M    (2 MB)
// w2bf = bf16 fc2 weights in MFMA B-frag layout:                 ws+10M   (0.5 MB)
// gt   = fp32 [128][156]                                         ws+11M   (78 KB)
// gpart= fp32 [512][64][64] fc2 logit partials (per kh-half)     ws+16M   (8 MB)
// R7 post-mortem: av IS resident (64 VGPR + acc in AGPRs, unified file) --
// the 6.4k cyc/chunk splits MFMA 1290 (16cyc/MFMA/SIMD) / LDS 1750 / VALU
// ~3000: VALU (addressing + loop overhead) is the biggest pipe. Also
// prep+conv = stable ~127us across all rounds > fused itself; conv has a
// structural LDS conflict (lanes tc,tc+8 share banks 4tc%32) on a ~15us
// port floor.
// R8: (1) conv v2: one channel/lane scalar reads (conflict-free), 128
// words/block, char-ids packed into Gs pad holes (78KiB -> 2 blocks/CU);
// (2) fused: unroll-4 chunk loop (static buf, cross-chunk ILP), drop
// setprio, drop last-chunk prefetch guard (overrun lands in w2bf; drained
// by the barrier before the epilogue overwrites it).

typedef __attribute__((ext_vector_type(8))) short short8;
typedef __attribute__((ext_vector_type(4))) float float4v;

__device__ inline short bf16b(float f) {
    __hip_bfloat16 h = __float2bfloat16(f);
    return *reinterpret_cast<short*>(&h);
}
__device__ inline uint packbf2(float a, float b) {
    return (uint)(ushort)bf16b(a) | ((uint)(ushort)bf16b(b) << 16);
}
__device__ inline void gload_lds16(const void* g, void* l) {
    __builtin_amdgcn_global_load_lds(
        (const __attribute__((address_space(1))) unsigned int*)g,
        (__attribute__((address_space(3))) unsigned int*)l, 16, 0, 0);
}

// ---------------------------------------------------------------------------
// Merged prep: wbf (blocks 0..4095), w2bf (..5119), gt (..5194), haPad (..5578)
// ---------------------------------------------------------------------------
__global__ __launch_bounds__(256) void prep_kernel(
    const float* __restrict__ fc1_w, const float* __restrict__ fc1_b,
    const float* __restrict__ fc2_w, const float* __restrict__ char_emb,
    const float* __restrict__ conv_w, short* __restrict__ wbf,
    short* __restrict__ w2bf, float* __restrict__ gt,
    __hip_bfloat16* __restrict__ ha)
{
    const int bid = blockIdx.x;
    if (bid < 4096) {                       // fc1 weights+bias -> frag order
        int idx = bid * 256 + threadIdx.x;  // n*256 + k
        int n = idx >> 8, k = idx & 255;
        float v = (k < 250) ? fc1_w[n * 250 + k] : (k == 250 ? fc1_b[n] : 0.f);
        int CT = n >> 4, mm = n & 15;
        int ks = k >> 5, qq = (k >> 3) & 3, j = k & 7;
        wbf[((CT * 8 + ks) * 64 + qq * 16 + mm) * 8 + j] = bf16b(v);
    } else if (bid < 5120) {                // fc2 weights (pad 64) -> frag order
        int idx = (bid - 4096) * 256 + threadIdx.x;   // o*4096 + k
        int o = idx >> 12, k = idx & 4095;
        float v = (o < 50) ? fc2_w[idx] : 0.f;
        int Ot = o >> 4, mm = o & 15;
        int kst = k >> 5, qq = (k >> 3) & 3, j = k & 7;
        w2bf[((kst * 4 + Ot) * 64 + qq * 16 + mm) * 8 + j] = bf16b(v);
    } else if (bid < 5195) {                // conv lookup table
        int idx = (bid - 5120) * 256 + threadIdx.x;   // < 19200
        if (idx >= 19200) return;
        int c = idx / 150, rem = idx - c * 150;
        int kk = rem / 50, o = rem - kk * 50;
        const float* ce = char_emb + c * 50;
        const float* w  = conv_w + o * 150 + kk;
        float s = 0.f;
        #pragma unroll 10
        for (int i = 0; i < 50; ++i) s += ce[i] * w[i * 3];
        gt[c * 156 + kk * 52 + o] = s;
    } else {                                // ha pad cols 250..255
        int idx = (bid - 5195) * 256 + threadIdx.x;   // b*6 + j
        int b = idx / 6, j = idx - b * 6;
        ha[b * 256 + 250 + j] = __float2bfloat16(j == 0 ? 1.f : 0.f);
    }
}

// ---------------------------------------------------------------------------
// conv v2: one channel per lane, conflict-free scalar LDS reads.
// 640 blocks x 512 thr; block = 128 words; wave handles 1 word per iter x16.
// Char ids (u8) + xid packed into the 2-float pad holes of each Gs row:
//   row w bytes w*624 + [200..207]=c0..7, [408..415]=c8..15,
//                       [616..619]=c16..19, [620..623]=xid.
// Tap address = c*624 + oc*4 (one v_mad) + imm {0,208,416}: zero addr VALU
// per tap. Banks = (c*156+oc+K)%32, oc consecutive -> <=2-way (free, m136).
// ---------------------------------------------------------------------------
__global__ __launch_bounds__(512) void conv_kernel(
    const int* __restrict__ x, const int* __restrict__ wci,
    const float* __restrict__ word_emb, const float* __restrict__ conv_b,
    const float* __restrict__ gt, __hip_bfloat16* __restrict__ ha)
{
    __shared__ float Gs[19968];           // 78 KiB -> 2 blocks/CU
    char* gsb = (char*)Gs;

    const int tid = threadIdx.x;
    const int gw0 = blockIdx.x * 128;

    #pragma unroll
    for (int t = 0; t < 39; ++t)
        Gs[t * 512 + tid] = gt[t * 512 + tid];
    __syncthreads();                       // rows (incl. pad holes) staged

    // pack char ids + xid into the pad holes of row `word`
    {
        const int word = tid >> 2, part = tid & 3;
        const int xid = x[gw0 + word];
        const int* crow = wci + (size_t)xid * 20 + part * 5;
        char* hole = gsb + word * 624;
        #pragma unroll
        for (int j = 0; j < 5; ++j) {
            const int p = part * 5 + j;
            const int off = (p < 8) ? 200 + p : (p < 16 ? 400 + p : 600 + p);
            hole[off] = (char)crow[j];
        }
        if (part == 0) *(int*)(hole + 620) = xid;
    }
    __syncthreads();

    const int lane = tid & 63;
    const int wv   = tid >> 6;
    const int oc   = (lane < 50) ? lane : 49;   // clamp keeps reads in-bounds
    const int oc4  = oc * 4;
    const float cbias = conv_b[oc];

    for (int it = 0; it < 16; ++it) {
        const int wl = it * 8 + wv;
        const char* hb = gsb + wl * 624;
        const uint cw0 = *(const uint*)(hb + 200);
        const uint cw1 = *(const uint*)(hb + 204);
        const uint cw2 = *(const uint*)(hb + 408);
        const uint cw3 = *(const uint*)(hb + 412);
        const uint cw4 = *(const uint*)(hb + 616);
        const int xid  = *(const int*)(hb + 620);

        int cb[20];
        #pragma unroll
        for (int p = 0; p < 20; ++p) {
            const uint cwv = (p < 4) ? cw0 : (p < 8) ? cw1 : (p < 12) ? cw2
                           : (p < 16) ? cw3 : cw4;
            const int c = (int)((cwv >> ((p & 3) * 8)) & 0xFF);
            cb[p] = c * 624 + oc4;
        }

        // S[l] = G[c_l][1] + G[c_{l-1}][0] + G[c_{l+1}][2]; max over l.
        // Add order matches R7 kernel exactly (center+prev+next; fp-add
        // commutativity of the first pair keeps it bit-identical).
        float mx = *(const float*)(gsb + cb[0] + 208)
                 + *(const float*)(gsb + cb[1] + 416);
        #pragma unroll
        for (int l = 1; l < 19; ++l) {
            float s = *(const float*)(gsb + cb[l] + 208)
                    + *(const float*)(gsb + cb[l - 1])
                    + *(const float*)(gsb + cb[l + 1] + 416);
            mx = fmaxf(mx, s);
        }
        {
            float s = *(const float*)(gsb + cb[19] + 208)
                    + *(const float*)(gsb + cb[18]);
            mx = fmaxf(mx, s);
        }

        const float wer = word_emb[(size_t)xid * 50 + oc];
        const float res = mx + cbias + wer;
        const int gw = gw0 + wl;
        const int b = gw / 5, wp = gw - b * 5;
        if (lane < 50)
            ha[b * 256 + wp * 50 + lane] = __float2bfloat16(res);
    }
}

// ---------------------------------------------------------------------------
// Fused fc1 + tanh + fc2-partial. 512 blocks x 512 thr. (R7 structure.)
// Block = (rg = bid>>1: 64 rows) x (kh = bid&1: 16 chunks of 128 h-cols).
// Waves 2x4: wr = wv>>2 (row half), wc = wv&3 (col quarter = fc2 k-frag).
// Wave-private hs handoff -> one __syncthreads per chunk (Bs dbuf flip).
// R8: unroll-4 (static buf, cross-chunk ILP), no setprio, unguarded last
// prefetch (lands in w2bf / overwritten after the vmcnt-draining barrier).
// ---------------------------------------------------------------------------
__global__ __launch_bounds__(512, 1) void fused_kernel(
    const __hip_bfloat16* __restrict__ ha, const short* __restrict__ wbf,
    const short* __restrict__ w2bf, float* __restrict__ gpart)
{
    __shared__ char smem[147456];                // 144 KB
    short8* Bsv = (short8*)smem;                 // [2][4096] frags (2x64KB)
    char*   hsb = smem + 131072;                 // 16 KB (16 frags)
    float*  partf = (float*)smem;                // [4][64][64] epilogue alias

    const int tid  = threadIdx.x;
    const int lane = tid & 63;
    const int wv   = tid >> 6;
    const int wr = wv >> 2, wc = wv & 3;
    const int q = lane >> 4, m = lane & 15;
    const int rg = blockIdx.x >> 1, kh = blockIdx.x & 1;
    const int m0 = rg * 64;
    const int q2base = q >> 1, slot = q & 1;

    const short8* wbfv  = (const short8*)wbf;
    const short8* w2bfv = (const short8*)w2bf;
    const short8* hav   = (const short8*)ha;

    // ---- A-frags: wave's 32 rows x K=256: 16 frags = 64 VGPR, pinned ----
    short8 av[2][8];
    #pragma unroll
    for (int mt = 0; mt < 2; ++mt)
        #pragma unroll
        for (int ks = 0; ks < 8; ++ks)
            av[mt][ks] = hav[(size_t)(m0 + wr * 32 + mt * 16 + m) * 32 + ks * 4 + q];
    #pragma unroll
    for (int mt = 0; mt < 2; ++mt)
        #pragma unroll
        for (int ks = 0; ks < 8; ++ks)
            asm volatile("" : "+v"(av[mt][ks]));

    // ---- prologue: stage chunk kh*16 into Bs[0] ----
    #pragma unroll
    for (int i = 0; i < 8; ++i)
        gload_lds16(wbfv + (size_t)(kh * 16) * 4096 + i * 512 + tid,
                    Bsv + i * 512 + tid);
    __syncthreads();

    float4v acc2[2][4] = {};    // fc2 partial: [row-tile mt][out-tile], k = wc

    #pragma unroll 4
    for (int chl = 0; chl < 16; ++chl) {
        const int buf = chl & 1;             // static within unrolled copies
        const int chg = kh * 16 + chl;

        // b2 for this chunk's wave k-frag (kst = chg*4 + wc), issued first
        short8 b2[4];
        #pragma unroll
        for (int Ot = 0; Ot < 4; ++Ot)
            b2[Ot] = w2bfv[(size_t)((chg * 4 + wc) * 4 + Ot) * 64 + lane];

        // async prefetch of next chunk (chl=15 overruns into w2bf: harmless,
        // drained by the final barrier, then overwritten by the epilogue)
        #pragma unroll
        for (int i = 0; i < 8; ++i)
            gload_lds16(wbfv + (size_t)(chg + 1) * 4096 + i * 512 + tid,
                        Bsv + (buf ^ 1) * 4096 + i * 512 + tid);

        // ---- fc1: rows [wr*32,+32) x cols [chg*128 + wc*32, +32) ----
        float4v acc[2][2] = {};
        #pragma unroll
        for (int ks = 0; ks < 8; ++ks) {
            short8 bv[2];
            #pragma unroll
            for (int nt = 0; nt < 2; ++nt)
                bv[nt] = Bsv[buf * 4096 + ((wc * 2 + nt) * 8 + ks) * 64 + lane];
            #pragma unroll
            for (int mt = 0; mt < 2; ++mt)
                #pragma unroll
                for (int nt = 0; nt < 2; ++nt)
                    acc[mt][nt] = __builtin_amdgcn_mfma_f32_16x16x32_bf16(
                        bv[nt], av[mt][ks], acc[mt][nt], 0, 0, 0);
        }

        // ---- tanh + pack to own hs frags (rt = wr*2+mt, kf = wc) ----
        #pragma unroll
        for (int mt = 0; mt < 2; ++mt) {
            const int frag = (wr * 2 + mt) * 4 + wc;
            #pragma unroll
            for (int nt = 0; nt < 2; ++nt) {
                float tv[4];
                #pragma unroll
                for (int r = 0; r < 4; ++r)
                    tv[r] = 1.f - 2.f / (__expf(2.f * acc[mt][nt][r]) + 1.f);
                const int q2 = nt * 2 + q2base;
                const uint p0 = packbf2(tv[0], tv[1]);
                const uint p1 = packbf2(tv[2], tv[3]);
                *(uint2*)(hsb + ((frag * 64 + q2 * 16 + m) * 16 + slot * 8))
                    = make_uint2(p0, p1);
            }
        }

        // ---- fc2 partial: read back OWN frags (same-wave order, no bar) ----
        {
            short8 a2[2];
            #pragma unroll
            for (int mt = 0; mt < 2; ++mt)
                a2[mt] = *(const short8*)(hsb
                    + (((wr * 2 + mt) * 4 + wc) * 64 + lane) * 16);
            #pragma unroll
            for (int mt = 0; mt < 2; ++mt)
                #pragma unroll
                for (int Ot = 0; Ot < 4; ++Ot)
                    acc2[mt][Ot] = __builtin_amdgcn_mfma_f32_16x16x32_bf16(
                        a2[mt], b2[Ot], acc2[mt][Ot], 0, 0, 0);
        }

        // single barrier: Bs[buf] reads done + prefetch vmcnt drained
        __syncthreads();
    }

    // ---- epilogue: spill per-wc k-partials, reduce, write gpart ----
    #pragma unroll
    for (int mt = 0; mt < 2; ++mt)
        #pragma unroll
        for (int Ot = 0; Ot < 4; ++Ot)
            #pragma unroll
            for (int r = 0; r < 4; ++r)
                partf[(size_t)wc * 4096
                      + ((wr * 2 + mt) * 16 + q * 4 + r) * 64 + Ot * 16 + m]
                    = acc2[mt][Ot][r];
    __syncthreads();

    #pragma unroll
    for (int t = 0; t < 8; ++t) {
        int idx = t * 512 + tid;           // row*64 + col
        float s = partf[idx] + partf[4096 + idx]
                + partf[8192 + idx] + partf[12288 + idx];
        gpart[(size_t)blockIdx.x * 4096 + idx] = s;
    }
}

// ---------------------------------------------------------------------------
// combine: sum the two kh halves, + bias, softmax, write out.
// ---------------------------------------------------------------------------
__global__ __launch_bounds__(256) void combine_kernel(
    const float* __restrict__ gpart, const float* __restrict__ fc2_b,
    float* __restrict__ out)
{
    const int tid  = threadIdx.x;
    const int lane = tid & 63;
    const int wv   = tid >> 6;
    const float bias = (lane < 50) ? fc2_b[lane] : 0.f;

    #pragma unroll
    for (int rr = 0; rr < 8; ++rr) {
        const int row = blockIdx.x * 32 + wv * 8 + rr;
        const int rg = row >> 6, rl = row & 63;
        float v = gpart[(size_t)(rg * 2) * 4096 + rl * 64 + lane]
                + gpart[(size_t)(rg * 2 + 1) * 4096 + rl * 64 + lane];
        v = (lane < 50) ? v + bias : -1e30f;
        float mx = v;
        #pragma unroll
        for (int off = 32; off > 0; off >>= 1) mx = fmaxf(mx, __shfl_xor(mx, off));
        float e = __expf(v - mx);
        float s = e;
        #pragma unroll
        for (int off = 32; off > 0; off >>= 1) s += __shfl_xor(s, off);
        if (lane < 50)
            out[(size_t)row * 50 + lane] = e / s;
    }
}

// ---------------------------------------------------------------------------
extern "C" void kernel_launch(void* const* d_in, const int* in_sizes, int n_in,
                              void* d_out, int out_size, void* d_ws, size_t ws_size,
                              hipStream_t stream) {
    const int*   x        = (const int*)  d_in[0];
    const int*   wci      = (const int*)  d_in[1];
    const float* word_emb = (const float*)d_in[2];
    const float* char_emb = (const float*)d_in[3];
    const float* conv_w   = (const float*)d_in[4];
    const float* conv_b   = (const float*)d_in[5];
    const float* fc1_w    = (const float*)d_in[6];
    const float* fc1_b    = (const float*)d_in[7];
    const float* fc2_w    = (const float*)d_in[8];
    const float* fc2_b    = (const float*)d_in[9];
    float* out = (float*)d_out;

    char* ws = (char*)d_ws;
    __hip_bfloat16* ha  = (__hip_bfloat16*)ws;                        // 8 MB
    short* wbf   = (short*)(ws + ((size_t)8  << 20));                 // 2 MB
    short* w2bf  = (short*)(ws + ((size_t)10 << 20));                 // 0.5 MB
    float* gtp   = (float*)(ws + ((size_t)11 << 20));                 // 78 KB
    float* gpart = (float*)(ws + ((size_t)16 << 20));                 // 8 MB

    prep_kernel<<<5579, 256, 0, stream>>>(fc1_w, fc1_b, fc2_w, char_emb,
                                          conv_w, wbf, w2bf, gtp, ha);
    conv_kernel<<<640, 512, 0, stream>>>(x, wci, word_emb, conv_b, gtp, ha);
    fused_kernel<<<512, 512, 0, stream>>>(ha, wbf, w2bf, gpart);
    combine_kernel<<<512, 256, 0, stream>>>(gpart, fc2_b, out);
}